// Round 1
// baseline (1830.534 us; speedup 1.0000x reference)
//
#include <hip/hip_runtime.h>
#include <stdint.h>

// ---------------------------------------------------------------------------
// MovingAverageGatedAttention (MEGA-style) forward, MI355X/gfx950.
// B=2 S=2048 D=2048 Z=512 HD=4096 H=8 N=8 ZH=64 VH=512 GROUPS=32
// Pipeline: tsn -> cema -> rms(mx) -> {z->q,k ; v=silu(tsn@wv) ; r=silu(mx@wr)}
//           -> flash attn (causal, dqk=64, dv=512) * r -> mx@wh1 + attn@wh2 + x
// bf16 MFMA for all GEMM-shaped compute; fp32 for the sequential scans.
// ---------------------------------------------------------------------------

typedef __bf16 bf16_t;
typedef bf16_t bf16x8 __attribute__((ext_vector_type(8)));
typedef float floatx4 __attribute__((ext_vector_type(4)));
typedef __attribute__((address_space(1))) unsigned int as1_uint;
typedef __attribute__((address_space(3))) unsigned int as3_uint;

static constexpr int kB = 2, kS = 2048, kD = 2048;
static constexpr int kZ = 512, kHD = 4096, kH = 8;
static constexpr int kG = 32;

__device__ __forceinline__ void async16(void* lds, const void* g) {
  // gfx950 direct global->LDS, 16B/lane. LDS dest = wave-uniform base + lane*16.
  __builtin_amdgcn_global_load_lds((const as1_uint*)(size_t)g, (as3_uint*)lds, 16, 0, 0);
}

__device__ __forceinline__ float sigm(float x) { return 1.0f / (1.0f + expf(-x)); }

// ---------------- weight fp32 (K,N) -> bf16 (N,K) transpose ----------------
__global__ __launch_bounds__(256) void wtrans_kernel(const float* __restrict__ W,
                                                     bf16_t* __restrict__ Wt,
                                                     int K, int N) {
  __shared__ float tile[32][33];
  int n0 = blockIdx.x * 32, k0 = blockIdx.y * 32;
  int tx = threadIdx.x & 31, ty = threadIdx.x >> 5;  // ty in 0..7
#pragma unroll
  for (int i = 0; i < 32; i += 8)
    tile[ty + i][tx] = W[(size_t)(k0 + ty + i) * N + n0 + tx];
  __syncthreads();
#pragma unroll
  for (int i = 0; i < 32; i += 8)
    Wt[(size_t)(n0 + ty + i) * K + k0 + tx] = (bf16_t)tile[tx][ty + i];
}

// ---------------- timestep norm: per-(b,s) group sums ----------------------
__global__ __launch_bounds__(256) void tsn_sums(const float* __restrict__ x,
                                                float* __restrict__ g1,
                                                float* __restrict__ g2) {
  int bs = blockIdx.x, t = threadIdx.x;
  const float4* rp = (const float4*)(x + (size_t)bs * kD + t * 8);
  float4 a = rp[0], b = rp[1];
  float s1 = a.x + a.y + a.z + a.w + b.x + b.y + b.z + b.w;
  float s2 = a.x * a.x + a.y * a.y + a.z * a.z + a.w * a.w +
             b.x * b.x + b.y * b.y + b.z * b.z + b.w * b.w;
  s1 += __shfl_xor(s1, 1); s2 += __shfl_xor(s2, 1);
  s1 += __shfl_xor(s1, 2); s2 += __shfl_xor(s2, 2);
  s1 += __shfl_xor(s1, 4); s2 += __shfl_xor(s2, 4);
  if ((t & 7) == 0) {
    int g = t >> 3, b_ = bs >> 11, s = bs & 2047;
    size_t idx = ((size_t)b_ * kG + g) * kS + s;   // [b][g][s] layout (scan-friendly)
    g1[idx] = s1; g2[idx] = s2;
  }
}

// ---------------- cumulative sum over s per (b,g) --------------------------
__global__ void tsn_scan(float* __restrict__ g1, float* __restrict__ g2) {
  int lane = threadIdx.x;  // 64 threads = 1 wave; blockIdx.x = b*32+g
  size_t base = (size_t)blockIdx.x * kS;
  float c1 = 0.f, c2 = 0.f;
  for (int c = 0; c < kS / 64; ++c) {
    size_t idx = base + c * 64 + lane;
    float v1 = g1[idx], v2 = g2[idx];
#pragma unroll
    for (int off = 1; off < 64; off <<= 1) {
      float t1 = __shfl_up(v1, off), t2 = __shfl_up(v2, off);
      if (lane >= off) { v1 += t1; v2 += t2; }
    }
    v1 += c1; v2 += c2;
    g1[idx] = v1; g2[idx] = v2;
    c1 = __shfl(v1, 63); c2 = __shfl(v2, 63);
  }
}

// ---------------- timestep norm apply (writes fp32 + bf16) -----------------
__global__ __launch_bounds__(256) void tsn_norm(const float* __restrict__ x,
    const float* __restrict__ g1, const float* __restrict__ g2,
    const float* __restrict__ w, const float* __restrict__ bias,
    float* __restrict__ tsn, bf16_t* __restrict__ tsnb) {
  int bs = blockIdx.x, t = threadIdx.x;
  int b = bs >> 11, s = bs & 2047, g = t >> 3;
  float cnt = (float)(s + 1) * 64.0f;
  size_t gidx = ((size_t)b * kG + g) * kS + s;
  float mean = g1[gidx] / cnt;
  float inv = rsqrtf(g2[gidx] / cnt - mean * mean + 1e-5f);
  size_t base = (size_t)bs * kD + t * 8;
  float4 a = ((const float4*)(x + base))[0];
  float4 c = ((const float4*)(x + base))[1];
  float v[8] = {a.x, a.y, a.z, a.w, c.x, c.y, c.z, c.w};
  float4 w0 = ((const float4*)(w + t * 8))[0], w1 = ((const float4*)(w + t * 8))[1];
  float4 b0 = ((const float4*)(bias + t * 8))[0], b1 = ((const float4*)(bias + t * 8))[1];
  float wv[8] = {w0.x, w0.y, w0.z, w0.w, w1.x, w1.y, w1.z, w1.w};
  float bv[8] = {b0.x, b0.y, b0.z, b0.w, b1.x, b1.y, b1.z, b1.w};
  float r[8];
  bf16x8 ob;
#pragma unroll
  for (int i = 0; i < 8; ++i) {
    r[i] = (v[i] - mean) * inv * wv[i] + bv[i];
    ob[i] = (bf16_t)r[i];
  }
  ((float4*)(tsn + base))[0] = make_float4(r[0], r[1], r[2], r[3]);
  ((float4*)(tsn + base))[1] = make_float4(r[4], r[5], r[6], r[7]);
  *(bf16x8*)(tsnb + base) = ob;
}

// ---------------- complex EMA scan: thread per (b,d,n) ---------------------
__global__ __launch_bounds__(256) void cema_kernel(const float* __restrict__ tsn,
    const float* __restrict__ alpha, const float* __restrict__ delta,
    const float* __restrict__ theta, const float* __restrict__ gamma,
    const float* __restrict__ omega, float* __restrict__ outc) {
  int tid = blockIdx.x * 256 + threadIdx.x;  // B*D*N = 32768 threads
  int n = tid & 7, d = (tid >> 3) & 2047, b = tid >> 14;
  int dn = d * 8 + n;
  float p = sigm(alpha[dn]);
  float qm = 1.0f - p * sigm(delta[dn]);
  float ph = sigm(theta[d]) * (0.78539816339744831f * (float)(n + 1));  // 2*pi*(n+1)/8
  float cs = cosf(ph), sn = sinf(ph);
  float ur = p * cs, ui = p * sn, qr = qm * cs, qi = qm * sn;
  float gr = gamma[dn * 2 + 0], gi = gamma[dn * 2 + 1];
  float om = omega[d];
  const float* xp = tsn + (size_t)b * kS * kD + d;
  float* op = outc + (size_t)b * kS * kD + d;
  float hr = 0.f, hi = 0.f;
  for (int s = 0; s < kS; ++s) {
    float xt = xp[(size_t)s * kD];
    float tr = fmaf(qr, hr, fmaf(-qi, hi, ur * xt));
    float ti = fmaf(qi, hr, fmaf(qr, hi, ui * xt));
    hr = tr; hi = ti;
    float y = fmaf(tr, gr, ti * gi);
    y += __shfl_xor(y, 1);
    y += __shfl_xor(y, 2);
    y += __shfl_xor(y, 4);
    if (n == 0) op[(size_t)s * kD] = y + xt * om;
  }
}

// ---------------- rmsnorm over D -> bf16 mx --------------------------------
__global__ __launch_bounds__(256) void rms_kernel(const float* __restrict__ in,
                                                  const float* __restrict__ w,
                                                  bf16_t* __restrict__ outb) {
  int bs = blockIdx.x, t = threadIdx.x;
  size_t base = (size_t)bs * kD + t * 8;
  float4 a = ((const float4*)(in + base))[0];
  float4 c = ((const float4*)(in + base))[1];
  float v[8] = {a.x, a.y, a.z, a.w, c.x, c.y, c.z, c.w};
  float ss = 0.f;
#pragma unroll
  for (int i = 0; i < 8; ++i) ss += v[i] * v[i];
#pragma unroll
  for (int off = 1; off < 64; off <<= 1) ss += __shfl_xor(ss, off);
  __shared__ float red[4];
  if ((t & 63) == 0) red[t >> 6] = ss;
  __syncthreads();
  ss = red[0] + red[1] + red[2] + red[3];
  float inv = rsqrtf(ss * (1.0f / 2048.0f) + 1e-5f);
  float4 w0 = ((const float4*)(w + t * 8))[0], w1 = ((const float4*)(w + t * 8))[1];
  float wv[8] = {w0.x, w0.y, w0.z, w0.w, w1.x, w1.y, w1.z, w1.w};
  bf16x8 ob;
#pragma unroll
  for (int i = 0; i < 8; ++i) ob[i] = (bf16_t)(v[i] * inv * wv[i]);
  *(bf16x8*)(outb + base) = ob;
}

// ---------------- z -> per-head rms -> gamma/beta -> rotary -> q,k bf16 ----
// q,k layout: [B][H][S][64]
__global__ __launch_bounds__(256) void zpost_kernel(const float* __restrict__ z,
    const float* __restrict__ ag, const float* __restrict__ ab,
    const float* __restrict__ freqs, bf16_t* __restrict__ q, bf16_t* __restrict__ k) {
  int bs = blockIdx.x, t = threadIdx.x;
  int b = bs >> 11, s = bs & 2047;
  int h = t >> 5, i = t & 31;  // head, rotary pair
  const float* zr = z + (size_t)bs * kZ + h * 64;
  float re = zr[2 * i], im = zr[2 * i + 1];
  float ss = re * re + im * im;
#pragma unroll
  for (int off = 1; off < 32; off <<= 1) ss += __shfl_xor(ss, off);
  float inv = rsqrtf(ss * (1.0f / 64.0f) + 1e-5f);
  float zne = re * inv, zno = im * inv;
  const float rs = 0.125f;  // 1/sqrt(64)
  int ze = h * 64 + 2 * i, zo = ze + 1;
  float qe = zne * ((ag[ze] + 1.f) * rs) + ab[ze];
  float qo = zno * ((ag[zo] + 1.f) * rs) + ab[zo];
  float ke = zne * ((ag[kZ + ze] + 1.f) * rs) + ab[kZ + ze];
  float ko = zno * ((ag[kZ + zo] + 1.f) * rs) + ab[kZ + zo];
  float cs = freqs[((size_t)s * 32 + i) * 2 + 0];
  float sn = freqs[((size_t)s * 32 + i) * 2 + 1];
  size_t o = (((size_t)b * kH + h) * kS + s) * 64 + 2 * i;
  q[o]     = (bf16_t)(qe * cs - qo * sn);
  q[o + 1] = (bf16_t)(qe * sn + qo * cs);
  k[o]     = (bf16_t)(ke * cs - ko * sn);
  k[o + 1] = (bf16_t)(ke * sn + ko * cs);
}

// ---------------- bf16 MFMA GEMM: C[M,N] = A[M,K] @ Bt[N,K]^T --------------
// 128x128 tile, BK=32, 4 waves each 64x64 (4x4 of 16x16x32). m97 structure.
// epi: 0 = +bias -> f32 ; 1 = silu(+bias) -> bf16 transposed vT[b][hd][s]
//      2 = silu(+bias) -> bf16 row-major ; 3 = + add1 + add2 -> f32
__global__ __launch_bounds__(256) void gemm_bt(const bf16_t* __restrict__ A,
    const bf16_t* __restrict__ Bt, int M, int N, int K,
    const float* __restrict__ bias, const float* __restrict__ add1,
    const float* __restrict__ add2, float* __restrict__ outF,
    bf16_t* __restrict__ outB, int epi) {
  __shared__ __align__(16) bf16_t sA[128 * 32];
  __shared__ __align__(16) bf16_t sB[128 * 32];
  const int t = threadIdx.x;
  const int wave = t >> 6, lane = t & 63;
  const int quad = lane >> 4, l16 = lane & 15;
  const int m0 = blockIdx.x * 128, n0 = blockIdx.y * 128;
  const int wm = (wave >> 1) * 64, wn = (wave & 1) * 64;

  floatx4 acc[4][4];
#pragma unroll
  for (int i = 0; i < 4; ++i)
#pragma unroll
    for (int j = 0; j < 4; ++j) acc[i][j] = (floatx4){0.f, 0.f, 0.f, 0.f};

  const int seg0 = wave * 64 + lane;        // segs 0..255
  const int seg1 = 256 + wave * 64 + lane;  // segs 256..511
  const int r0 = seg0 >> 2, c0 = (seg0 & 3) * 8;
  const int r1 = seg1 >> 2, c1 = (seg1 & 3) * 8;

  for (int kt = 0; kt < K; kt += 32) {
    __syncthreads();
    async16(sA + (size_t)(wave * 64) * 8,        A + (size_t)(m0 + r0) * K + kt + c0);
    async16(sA + (size_t)(256 + wave * 64) * 8,  A + (size_t)(m0 + r1) * K + kt + c1);
    async16(sB + (size_t)(wave * 64) * 8,        Bt + (size_t)(n0 + r0) * K + kt + c0);
    async16(sB + (size_t)(256 + wave * 64) * 8,  Bt + (size_t)(n0 + r1) * K + kt + c1);
    __syncthreads();  // compiler drains vmcnt before s_barrier

    bf16x8 af[4], bfr[4];
#pragma unroll
    for (int i = 0; i < 4; ++i)
      af[i] = *(const bf16x8*)(sA + (wm + i * 16 + l16) * 32 + quad * 8);
#pragma unroll
    for (int j = 0; j < 4; ++j)
      bfr[j] = *(const bf16x8*)(sB + (wn + j * 16 + l16) * 32 + quad * 8);
#pragma unroll
    for (int i = 0; i < 4; ++i)
#pragma unroll
      for (int j = 0; j < 4; ++j)
        acc[i][j] = __builtin_amdgcn_mfma_f32_16x16x32_bf16(af[i], bfr[j], acc[i][j], 0, 0, 0);
  }

  // epilogue: C/D layout col=l16, row=quad*4+reg
#pragma unroll
  for (int i = 0; i < 4; ++i) {
#pragma unroll
    for (int j = 0; j < 4; ++j) {
#pragma unroll
      for (int r = 0; r < 4; ++r) {
        int row = m0 + wm + i * 16 + quad * 4 + r;
        int col = n0 + wn + j * 16 + l16;
        size_t idx = (size_t)row * N + col;
        float v = acc[i][j][r];
        if (epi == 0) {
          outF[idx] = v + bias[col];
        } else if (epi == 1) {
          v += bias[col];
          v = v / (1.f + __expf(-v));
          // vT[b][hd][s] : hd = col (0..4095), b = row>>11, s = row&2047
          size_t vidx = ((size_t)(row >> 11) * kHD + col) * (size_t)kS + (row & 2047);
          outB[vidx] = (bf16_t)v;
        } else if (epi == 2) {
          v += bias[col];
          v = v / (1.f + __expf(-v));
          outB[idx] = (bf16_t)v;
        } else {
          outF[idx] = v + add1[idx] + add2[idx];
        }
      }
    }
  }
}

// ---------------- flash attention (causal) + r-gating ----------------------
// grid: (S/64, B*H). block 256 = 4 waves. Wave w: scores for q-rows w*16..+16,
// PV for vh chunk w*128..+128 over all 64 q-rows. P via LDS (bf16).
// q,k: [B][H][S][64] bf16 ; vT: [B][HD][S] bf16 (per (b,h): rows h*512..)
// r, attnG: [B][S][HD] bf16.
__global__ __launch_bounds__(256) void attn_kernel(const bf16_t* __restrict__ qg,
    const bf16_t* __restrict__ kg, const bf16_t* __restrict__ vT,
    const bf16_t* __restrict__ rg, bf16_t* __restrict__ attnG) {
  const int qt = blockIdx.x, bh = blockIdx.y;
  const int b = bh >> 3, h = bh & 7;
  const int t = threadIdx.x;
  const int w = t >> 6, lane = t & 63;
  const int quad = lane >> 4, l16 = lane & 15;
  const int q0 = qt * 64;

  __shared__ __align__(16) bf16_t sP[64 * 64];
  __shared__ float sM[64], sL[64], sAl[64];
  if (t < 64) { sM[t] = -1e30f; sL[t] = 0.f; }

  const bf16_t* qbase = qg + ((size_t)bh * kS + q0) * 64;
  bf16x8 qfrag[2];
#pragma unroll
  for (int ks = 0; ks < 2; ++ks)
    qfrag[ks] = *(const bf16x8*)(qbase + (size_t)(w * 16 + l16) * 64 + ks * 32 + quad * 8);

  floatx4 oacc[4][8];
#pragma unroll
  for (int i = 0; i < 4; ++i)
#pragma unroll
    for (int j = 0; j < 8; ++j) oacc[i][j] = (floatx4){0.f, 0.f, 0.f, 0.f};

  const bf16_t* kbase = kg + (size_t)bh * kS * 64;
  const bf16_t* vbase = vT + (size_t)bh * 512 * kS;  // (b*8+h)*512 rows of vT[b][hd][s]

  __syncthreads();

  for (int kt = 0; kt <= qt; ++kt) {
    const int k0 = kt * 64;
    floatx4 sacc[4];
#pragma unroll
    for (int nt = 0; nt < 4; ++nt) sacc[nt] = (floatx4){0.f, 0.f, 0.f, 0.f};
#pragma unroll
    for (int ks = 0; ks < 2; ++ks)
#pragma unroll
      for (int nt = 0; nt < 4; ++nt) {
        bf16x8 kf = *(const bf16x8*)(kbase + (size_t)(k0 + nt * 16 + l16) * 64 + ks * 32 + quad * 8);
        sacc[nt] = __builtin_amdgcn_mfma_f32_16x16x32_bf16(qfrag[ks], kf, sacc[nt], 0, 0, 0);
      }
    if (kt == qt) {  // causal mask on diagonal tile
#pragma unroll
      for (int nt = 0; nt < 4; ++nt)
#pragma unroll
        for (int r = 0; r < 4; ++r) {
          int sk = k0 + nt * 16 + l16;
          int qq = q0 + w * 16 + quad * 4 + r;
          if (sk > qq) sacc[nt][r] = -1e30f;
        }
    }
    float mloc[4], mnew[4], al[4], lloc[4];
#pragma unroll
    for (int r = 0; r < 4; ++r)
      mloc[r] = fmaxf(fmaxf(sacc[0][r], sacc[1][r]), fmaxf(sacc[2][r], sacc[3][r]));
#pragma unroll
    for (int off = 1; off < 16; off <<= 1)
#pragma unroll
      for (int r = 0; r < 4; ++r) mloc[r] = fmaxf(mloc[r], __shfl_xor(mloc[r], off));
#pragma unroll
    for (int r = 0; r < 4; ++r) {
      int row = w * 16 + quad * 4 + r;
      float mo = sM[row];
      mnew[r] = fmaxf(mo, mloc[r]);
      al[r] = __expf(mo - mnew[r]);
    }
#pragma unroll
    for (int r = 0; r < 4; ++r) {
      float s = 0.f;
#pragma unroll
      for (int nt = 0; nt < 4; ++nt) {
        float e = __expf(sacc[nt][r] - mnew[r]);
        sacc[nt][r] = e;
        s += e;
      }
      lloc[r] = s;
    }
#pragma unroll
    for (int off = 1; off < 16; off <<= 1)
#pragma unroll
      for (int r = 0; r < 4; ++r) lloc[r] += __shfl_xor(lloc[r], off);
    if (l16 == 0) {
#pragma unroll
      for (int r = 0; r < 4; ++r) {
        int row = w * 16 + quad * 4 + r;
        sM[row] = mnew[r];
        sL[row] = al[r] * sL[row] + lloc[r];
        sAl[row] = al[r];
      }
    }
#pragma unroll
    for (int nt = 0; nt < 4; ++nt)
#pragma unroll
      for (int r = 0; r < 4; ++r)
        sP[(w * 16 + quad * 4 + r) * 64 + nt * 16 + l16] = (bf16_t)sacc[nt][r];
    __syncthreads();

    // rescale O then accumulate P @ V
#pragma unroll
    for (int mi = 0; mi < 4; ++mi)
#pragma unroll
      for (int r = 0; r < 4; ++r) {
        float a = sAl[mi * 16 + quad * 4 + r];
#pragma unroll
        for (int nj = 0; nj < 8; ++nj) oacc[mi][nj][r] *= a;
      }
#pragma unroll
    for (int ks = 0; ks < 2; ++ks) {
      bf16x8 pa[4];
#pragma unroll
      for (int mi = 0; mi < 4; ++mi)
        pa[mi] = *(const bf16x8*)(sP + (mi * 16 + l16) * 64 + ks * 32 + quad * 8);
#pragma unroll
      for (int nj = 0; nj < 8; ++nj) {
        bf16x8 vf = *(const bf16x8*)(vbase + (size_t)(w * 128 + nj * 16 + l16) * kS + k0 + ks * 32 + quad * 8);
#pragma unroll
        for (int mi = 0; mi < 4; ++mi)
          oacc[mi][nj] = __builtin_amdgcn_mfma_f32_16x16x32_bf16(pa[mi], vf, oacc[mi][nj], 0, 0, 0);
      }
    }
    __syncthreads();
  }

  // epilogue: O/l * r -> attnG bf16
#pragma unroll
  for (int mi = 0; mi < 4; ++mi)
#pragma unroll
    for (int r = 0; r < 4; ++r) {
      int srow = q0 + mi * 16 + quad * 4 + r;
      float linv = 1.0f / sL[mi * 16 + quad * 4 + r];
#pragma unroll
      for (int nj = 0; nj < 8; ++nj) {
        int hd = h * 512 + w * 128 + nj * 16 + l16;
        size_t idx = ((size_t)b * kS + srow) * kHD + hd;
        float rv = (float)rg[idx];
        attnG[idx] = (bf16_t)(oacc[mi][nj][r] * linv * rv);
      }
    }
}

// ---------------------------------------------------------------------------
extern "C" void kernel_launch(void* const* d_in, const int* in_sizes, int n_in,
                              void* d_out, int out_size, void* d_ws, size_t ws_size,
                              hipStream_t stream) {
  const float* x      = (const float*)d_in[0];
  const float* tnw    = (const float*)d_in[1];
  const float* tnb    = (const float*)d_in[2];
  const float* ealpha = (const float*)d_in[3];
  const float* edelta = (const float*)d_in[4];
  const float* etheta = (const float*)d_in[5];
  const float* egamma = (const float*)d_in[6];
  const float* eomega = (const float*)d_in[7];
  const float* rmsw   = (const float*)d_in[8];
  const float* wz_w   = (const float*)d_in[9];
  const float* wz_b   = (const float*)d_in[10];
  const float* wv_w   = (const float*)d_in[11];
  const float* wv_b   = (const float*)d_in[12];
  const float* wr_w   = (const float*)d_in[13];
  const float* wr_b   = (const float*)d_in[14];
  const float* wh1_w  = (const float*)d_in[15];
  const float* wh1_b  = (const float*)d_in[16];
  const float* wh2_w  = (const float*)d_in[17];
  const float* ag     = (const float*)d_in[18];
  const float* ab     = (const float*)d_in[19];
  const float* freqs  = (const float*)d_in[20];
  float* out = (float*)d_out;

  char* ws = (char*)d_ws;
  size_t off = 0;
  auto alloc = [&](size_t bytes) -> void* {
    void* p = ws + off;
    off += (bytes + 255) & ~(size_t)255;
    return p;
  };
  // buf1: tsn fp32, later reused as vT bf16 (tsn fp32 dead after cema)
  float*  tsn  = (float*)alloc(8388608ull * 4);
  bf16_t* tsnb = (bf16_t*)alloc(8388608ull * 2);
  float*  g1   = (float*)alloc(131072ull * 4);
  float*  g2   = (float*)alloc(131072ull * 4);
  // buf2: cema fp32, later reused as h1 fp32 (cema dead after rms)
  float*  cema = (float*)alloc(8388608ull * 4);
  bf16_t* mx   = (bf16_t*)alloc(8388608ull * 2);
  bf16_t* wzT  = (bf16_t*)alloc(1048576ull * 2);
  bf16_t* wvT  = (bf16_t*)alloc(8388608ull * 2);
  bf16_t* wrT  = (bf16_t*)alloc(8388608ull * 2);
  bf16_t* wh1T = (bf16_t*)alloc(4194304ull * 2);
  bf16_t* wh2T = (bf16_t*)alloc(8388608ull * 2);
  float*  zbuf = (float*)alloc(2097152ull * 4);
  bf16_t* qb   = (bf16_t*)alloc(2097152ull * 2);
  bf16_t* kb   = (bf16_t*)alloc(2097152ull * 2);
  bf16_t* rb   = (bf16_t*)alloc(16777216ull * 2);
  bf16_t* aG   = (bf16_t*)alloc(16777216ull * 2);
  bf16_t* vTb  = (bf16_t*)tsn;   // alias buf1 (16.8M bf16 fits in 33.5MB)
  float*  h1   = cema;           // alias buf2

  // weights -> bf16, transposed to (N,K)
  wtrans_kernel<<<dim3(kZ / 32, kD / 32), 256, 0, stream>>>(wz_w, wzT, kD, kZ);
  wtrans_kernel<<<dim3(kHD / 32, kD / 32), 256, 0, stream>>>(wv_w, wvT, kD, kHD);
  wtrans_kernel<<<dim3(kHD / 32, kD / 32), 256, 0, stream>>>(wr_w, wrT, kD, kHD);
  wtrans_kernel<<<dim3(kD / 32, kD / 32), 256, 0, stream>>>(wh1_w, wh1T, kD, kD);
  wtrans_kernel<<<dim3(kD / 32, kHD / 32), 256, 0, stream>>>(wh2_w, wh2T, kHD, kD);

  // timestep norm
  tsn_sums<<<kB * kS, 256, 0, stream>>>(x, g1, g2);
  tsn_scan<<<kB * kG, 64, 0, stream>>>(g1, g2);
  tsn_norm<<<kB * kS, 256, 0, stream>>>(x, g1, g2, tnw, tnb, tsn, tsnb);

  // complex EMA + residual omega
  cema_kernel<<<kB * kD * 8 / 256, 256, 0, stream>>>(tsn, ealpha, edelta, etheta,
                                                     egamma, eomega, cema);
  // mx = rmsnorm(cema) -> bf16
  rms_kernel<<<kB * kS, 256, 0, stream>>>(cema, rmsw, mx);

  const int M = kB * kS;  // 4096
  // z = mx @ wz + b
  gemm_bt<<<dim3(M / 128, kZ / 128), 256, 0, stream>>>(mx, wzT, M, kZ, kD,
      wz_b, nullptr, nullptr, zbuf, nullptr, 0);
  // z -> q,k (per-head rms, gamma/beta, rotary)
  zpost_kernel<<<kB * kS, 256, 0, stream>>>(zbuf, ag, ab, freqs, qb, kb);
  // v = silu(tsn @ wv + b) -> vT[b][hd][s]   (NOTE: after cema; buf1 reuse OK)
  gemm_bt<<<dim3(M / 128, kHD / 128), 256, 0, stream>>>(tsnb, wvT, M, kHD, kD,
      wv_b, nullptr, nullptr, nullptr, vTb, 1);
  // r = silu(mx @ wr + b) -> bf16 row-major
  gemm_bt<<<dim3(M / 128, kHD / 128), 256, 0, stream>>>(mx, wrT, M, kHD, kD,
      wr_b, nullptr, nullptr, nullptr, rb, 2);
  // attention + gating
  attn_kernel<<<dim3(kS / 64, kB * kH), 256, 0, stream>>>(qb, kb, vTb, rb, aG);
  // h1 = mx @ wh1 + b
  gemm_bt<<<dim3(M / 128, kD / 128), 256, 0, stream>>>(mx, wh1T, M, kD, kD,
      wh1_b, nullptr, nullptr, h1, nullptr, 0);
  // out = attnG @ wh2 + h1 + x
  gemm_bt<<<dim3(M / 128, kD / 128), 256, 0, stream>>>(aG, wh2T, M, kD, kHD,
      nullptr, h1, x, out, nullptr, 3);
  (void)in_sizes; (void)n_in; (void)out_size; (void)ws_size;
}

// Round 2
// 1184.164 us; speedup vs baseline: 1.5458x; 1.5458x over previous
//
#include <hip/hip_runtime.h>
#include <stdint.h>

// ---------------------------------------------------------------------------
// MovingAverageGatedAttention (MEGA-style) forward, MI355X/gfx950.
// B=2 S=2048 D=2048 Z=512 HD=4096 H=8 N=8 ZH=64 VH=512 GROUPS=32
// Pipeline: tsn -> cema -> rms(mx) -> {z->q,k ; v=silu(tsn@wv) ; r=silu(mx@wr)}
//           -> flash attn (causal, dqk=64, dv=512) * r -> mx@wh1 + attn@wh2 + x
// bf16 MFMA for all GEMM-shaped compute; fp32 for the sequential scans.
// R1: cema rewritten as chunked parallel linear scan (64 chunks x 32 steps,
//     3 passes) — old single-pass version was latency-bound at 728us.
// ---------------------------------------------------------------------------

typedef __bf16 bf16_t;
typedef bf16_t bf16x8 __attribute__((ext_vector_type(8)));
typedef float floatx4 __attribute__((ext_vector_type(4)));
typedef __attribute__((address_space(1))) unsigned int as1_uint;
typedef __attribute__((address_space(3))) unsigned int as3_uint;

static constexpr int kB = 2, kS = 2048, kD = 2048;
static constexpr int kZ = 512, kHD = 4096, kH = 8;
static constexpr int kG = 32;
static constexpr int kC = 64, kL = 32;  // cema: chunks, chunk length (kC*kL==kS)

__device__ __forceinline__ void async16(void* lds, const void* g) {
  // gfx950 direct global->LDS, 16B/lane. LDS dest = wave-uniform base + lane*16.
  __builtin_amdgcn_global_load_lds((const as1_uint*)(size_t)g, (as3_uint*)lds, 16, 0, 0);
}

__device__ __forceinline__ float sigm(float x) { return 1.0f / (1.0f + expf(-x)); }

// ---------------- weight fp32 (K,N) -> bf16 (N,K) transpose ----------------
__global__ __launch_bounds__(256) void wtrans_kernel(const float* __restrict__ W,
                                                     bf16_t* __restrict__ Wt,
                                                     int K, int N) {
  __shared__ float tile[32][33];
  int n0 = blockIdx.x * 32, k0 = blockIdx.y * 32;
  int tx = threadIdx.x & 31, ty = threadIdx.x >> 5;  // ty in 0..7
#pragma unroll
  for (int i = 0; i < 32; i += 8)
    tile[ty + i][tx] = W[(size_t)(k0 + ty + i) * N + n0 + tx];
  __syncthreads();
#pragma unroll
  for (int i = 0; i < 32; i += 8)
    Wt[(size_t)(n0 + ty + i) * K + k0 + tx] = (bf16_t)tile[tx][ty + i];
}

// ---------------- timestep norm: per-(b,s) group sums ----------------------
__global__ __launch_bounds__(256) void tsn_sums(const float* __restrict__ x,
                                                float* __restrict__ g1,
                                                float* __restrict__ g2) {
  int bs = blockIdx.x, t = threadIdx.x;
  const float4* rp = (const float4*)(x + (size_t)bs * kD + t * 8);
  float4 a = rp[0], b = rp[1];
  float s1 = a.x + a.y + a.z + a.w + b.x + b.y + b.z + b.w;
  float s2 = a.x * a.x + a.y * a.y + a.z * a.z + a.w * a.w +
             b.x * b.x + b.y * b.y + b.z * b.z + b.w * b.w;
  s1 += __shfl_xor(s1, 1); s2 += __shfl_xor(s2, 1);
  s1 += __shfl_xor(s1, 2); s2 += __shfl_xor(s2, 2);
  s1 += __shfl_xor(s1, 4); s2 += __shfl_xor(s2, 4);
  if ((t & 7) == 0) {
    int g = t >> 3, b_ = bs >> 11, s = bs & 2047;
    size_t idx = ((size_t)b_ * kG + g) * kS + s;   // [b][g][s] layout (scan-friendly)
    g1[idx] = s1; g2[idx] = s2;
  }
}

// ---------------- cumulative sum over s per (b,g) --------------------------
__global__ void tsn_scan(float* __restrict__ g1, float* __restrict__ g2) {
  int lane = threadIdx.x;  // 64 threads = 1 wave; blockIdx.x = b*32+g
  size_t base = (size_t)blockIdx.x * kS;
  float c1 = 0.f, c2 = 0.f;
  for (int c = 0; c < kS / 64; ++c) {
    size_t idx = base + c * 64 + lane;
    float v1 = g1[idx], v2 = g2[idx];
#pragma unroll
    for (int off = 1; off < 64; off <<= 1) {
      float t1 = __shfl_up(v1, off), t2 = __shfl_up(v2, off);
      if (lane >= off) { v1 += t1; v2 += t2; }
    }
    v1 += c1; v2 += c2;
    g1[idx] = v1; g2[idx] = v2;
    c1 = __shfl(v1, 63); c2 = __shfl(v2, 63);
  }
}

// ---------------- timestep norm apply (writes fp32 + bf16) -----------------
__global__ __launch_bounds__(256) void tsn_norm(const float* __restrict__ x,
    const float* __restrict__ g1, const float* __restrict__ g2,
    const float* __restrict__ w, const float* __restrict__ bias,
    float* __restrict__ tsn, bf16_t* __restrict__ tsnb) {
  int bs = blockIdx.x, t = threadIdx.x;
  int b = bs >> 11, s = bs & 2047, g = t >> 3;
  float cnt = (float)(s + 1) * 64.0f;
  size_t gidx = ((size_t)b * kG + g) * kS + s;
  float mean = g1[gidx] / cnt;
  float inv = rsqrtf(g2[gidx] / cnt - mean * mean + 1e-5f);
  size_t base = (size_t)bs * kD + t * 8;
  float4 a = ((const float4*)(x + base))[0];
  float4 c = ((const float4*)(x + base))[1];
  float v[8] = {a.x, a.y, a.z, a.w, c.x, c.y, c.z, c.w};
  float4 w0 = ((const float4*)(w + t * 8))[0], w1 = ((const float4*)(w + t * 8))[1];
  float4 b0 = ((const float4*)(bias + t * 8))[0], b1 = ((const float4*)(bias + t * 8))[1];
  float wv[8] = {w0.x, w0.y, w0.z, w0.w, w1.x, w1.y, w1.z, w1.w};
  float bv[8] = {b0.x, b0.y, b0.z, b0.w, b1.x, b1.y, b1.z, b1.w};
  float r[8];
  bf16x8 ob;
#pragma unroll
  for (int i = 0; i < 8; ++i) {
    r[i] = (v[i] - mean) * inv * wv[i] + bv[i];
    ob[i] = (bf16_t)r[i];
  }
  ((float4*)(tsn + base))[0] = make_float4(r[0], r[1], r[2], r[3]);
  ((float4*)(tsn + base))[1] = make_float4(r[4], r[5], r[6], r[7]);
  *(bf16x8*)(tsnb + base) = ob;
}

// ---------------- complex EMA, chunked parallel scan -----------------------
// Linear recurrence h_s = q h_{s-1} + u x_s  =>  h_end(chunk) = q^L h_init + h_local.
// pass1: per (b,chunk,d) run L steps from h=0, save 8 complex end states.
// pass2: per (b,d,n) scan carries across 64 chunks with coeff q^L.
// pass3: per (b,chunk,d) rerun L steps from carry, emit y.

__device__ __forceinline__ void cema_coeffs(const float* __restrict__ alpha,
    const float* __restrict__ delta, float st, int d,
    float (&qr)[8], float (&qi)[8], float (&ur)[8], float (&ui)[8]) {
  const float4* ap = (const float4*)(alpha + (size_t)d * 8);
  const float4* dp = (const float4*)(delta + (size_t)d * 8);
  float4 a0 = ap[0], a1 = ap[1], d0 = dp[0], d1 = dp[1];
  float av[8] = {a0.x, a0.y, a0.z, a0.w, a1.x, a1.y, a1.z, a1.w};
  float dv[8] = {d0.x, d0.y, d0.z, d0.w, d1.x, d1.y, d1.z, d1.w};
#pragma unroll
  for (int n = 0; n < 8; ++n) {
    float p = sigm(av[n]);
    float qm = 1.0f - p * sigm(dv[n]);
    float ph = st * (0.78539816339744831f * (float)(n + 1));  // 2*pi*(n+1)/8
    float cs = cosf(ph), sn = sinf(ph);
    qr[n] = qm * cs; qi[n] = qm * sn;
    ur[n] = p * cs;  ui[n] = p * sn;
  }
}

__global__ __launch_bounds__(256) void cema_pass1(const float* __restrict__ tsn,
    const float* __restrict__ alpha, const float* __restrict__ delta,
    const float* __restrict__ theta, float2* __restrict__ hend) {
  int b = blockIdx.x >> 6, c = blockIdx.x & 63;
  int d = blockIdx.y * 256 + threadIdx.x;
  float st = sigm(theta[d]);
  float qr[8], qi[8], ur[8], ui[8];
  cema_coeffs(alpha, delta, st, d, qr, qi, ur, ui);
  float hr[8] = {0}, hi[8] = {0};
  const float* xp = tsn + ((size_t)b * kS + c * kL) * kD + d;
  for (int i = 0; i < kL; ++i) {
    float xt = xp[(size_t)i * kD];
#pragma unroll
    for (int n = 0; n < 8; ++n) {
      float tr = fmaf(qr[n], hr[n], fmaf(-qi[n], hi[n], ur[n] * xt));
      float ti = fmaf(qi[n], hr[n], fmaf(qr[n], hi[n], ui[n] * xt));
      hr[n] = tr; hi[n] = ti;
    }
  }
  float2* op = hend + (((size_t)(b * kC + c)) * kD + d) * 8;
#pragma unroll
  for (int n = 0; n < 8; ++n) op[n] = make_float2(hr[n], hi[n]);
}

__global__ __launch_bounds__(256) void cema_pass2(const float2* __restrict__ hend,
    const float* __restrict__ alpha, const float* __restrict__ delta,
    const float* __restrict__ theta, float2* __restrict__ hinit) {
  int tid = blockIdx.x * 256 + threadIdx.x;  // b*D*8 + d*8 + n
  int n = tid & 7, d = (tid >> 3) & 2047, b = tid >> 14;
  int dn = d * 8 + n;
  float p = sigm(alpha[dn]);
  float qm = 1.0f - p * sigm(delta[dn]);
  float ph = sigm(theta[d]) * (0.78539816339744831f * (float)(n + 1));
  float ar = qm * cosf(ph), ai = qm * sinf(ph);
  // q^L via repeated squaring (L=32 -> 5 squarings)
#pragma unroll
  for (int t = 0; t < 5; ++t) {
    float nr = ar * ar - ai * ai;
    ai = 2.0f * ar * ai;
    ar = nr;
  }
  float hr = 0.f, hi = 0.f;
  for (int c = 0; c < kC; ++c) {
    size_t idx = (((size_t)(b * kC + c)) * kD + d) * 8 + n;
    hinit[idx] = make_float2(hr, hi);
    float2 e = hend[idx];
    float nr = fmaf(ar, hr, fmaf(-ai, hi, e.x));
    float ni = fmaf(ai, hr, fmaf(ar, hi, e.y));
    hr = nr; hi = ni;
  }
}

__global__ __launch_bounds__(256) void cema_pass3(const float* __restrict__ tsn,
    const float* __restrict__ alpha, const float* __restrict__ delta,
    const float* __restrict__ theta, const float* __restrict__ gamma,
    const float* __restrict__ omega, const float2* __restrict__ hinit,
    float* __restrict__ outc) {
  int b = blockIdx.x >> 6, c = blockIdx.x & 63;
  int d = blockIdx.y * 256 + threadIdx.x;
  float st = sigm(theta[d]);
  float qr[8], qi[8], ur[8], ui[8];
  cema_coeffs(alpha, delta, st, d, qr, qi, ur, ui);
  float gr[8], gi[8];
  const float4* gp = (const float4*)(gamma + (size_t)d * 16);
#pragma unroll
  for (int m = 0; m < 4; ++m) {
    float4 g = gp[m];
    gr[m * 2] = g.x; gi[m * 2] = g.y; gr[m * 2 + 1] = g.z; gi[m * 2 + 1] = g.w;
  }
  float om = omega[d];
  float hr[8], hi[8];
  const float2* ip = hinit + (((size_t)(b * kC + c)) * kD + d) * 8;
#pragma unroll
  for (int n = 0; n < 8; ++n) { float2 h = ip[n]; hr[n] = h.x; hi[n] = h.y; }
  const float* xp = tsn + ((size_t)b * kS + c * kL) * kD + d;
  float* op = outc + ((size_t)b * kS + c * kL) * kD + d;
  for (int i = 0; i < kL; ++i) {
    float xt = xp[(size_t)i * kD];
    float y = 0.f;
#pragma unroll
    for (int n = 0; n < 8; ++n) {
      float tr = fmaf(qr[n], hr[n], fmaf(-qi[n], hi[n], ur[n] * xt));
      float ti = fmaf(qi[n], hr[n], fmaf(qr[n], hi[n], ui[n] * xt));
      hr[n] = tr; hi[n] = ti;
      y = fmaf(tr, gr[n], fmaf(ti, gi[n], y));
    }
    op[(size_t)i * kD] = fmaf(xt, om, y);
  }
}

// ---------------- rmsnorm over D -> bf16 mx --------------------------------
__global__ __launch_bounds__(256) void rms_kernel(const float* __restrict__ in,
                                                  const float* __restrict__ w,
                                                  bf16_t* __restrict__ outb) {
  int bs = blockIdx.x, t = threadIdx.x;
  size_t base = (size_t)bs * kD + t * 8;
  float4 a = ((const float4*)(in + base))[0];
  float4 c = ((const float4*)(in + base))[1];
  float v[8] = {a.x, a.y, a.z, a.w, c.x, c.y, c.z, c.w};
  float ss = 0.f;
#pragma unroll
  for (int i = 0; i < 8; ++i) ss += v[i] * v[i];
#pragma unroll
  for (int off = 1; off < 64; off <<= 1) ss += __shfl_xor(ss, off);
  __shared__ float red[4];
  if ((t & 63) == 0) red[t >> 6] = ss;
  __syncthreads();
  ss = red[0] + red[1] + red[2] + red[3];
  float inv = rsqrtf(ss * (1.0f / 2048.0f) + 1e-5f);
  float4 w0 = ((const float4*)(w + t * 8))[0], w1 = ((const float4*)(w + t * 8))[1];
  float wv[8] = {w0.x, w0.y, w0.z, w0.w, w1.x, w1.y, w1.z, w1.w};
  bf16x8 ob;
#pragma unroll
  for (int i = 0; i < 8; ++i) ob[i] = (bf16_t)(v[i] * inv * wv[i]);
  *(bf16x8*)(outb + base) = ob;
}

// ---------------- z -> per-head rms -> gamma/beta -> rotary -> q,k bf16 ----
// q,k layout: [B][H][S][64]
__global__ __launch_bounds__(256) void zpost_kernel(const float* __restrict__ z,
    const float* __restrict__ ag, const float* __restrict__ ab,
    const float* __restrict__ freqs, bf16_t* __restrict__ q, bf16_t* __restrict__ k) {
  int bs = blockIdx.x, t = threadIdx.x;
  int b = bs >> 11, s = bs & 2047;
  int h = t >> 5, i = t & 31;  // head, rotary pair
  const float* zr = z + (size_t)bs * kZ + h * 64;
  float re = zr[2 * i], im = zr[2 * i + 1];
  float ss = re * re + im * im;
#pragma unroll
  for (int off = 1; off < 32; off <<= 1) ss += __shfl_xor(ss, off);
  float inv = rsqrtf(ss * (1.0f / 64.0f) + 1e-5f);
  float zne = re * inv, zno = im * inv;
  const float rs = 0.125f;  // 1/sqrt(64)
  int ze = h * 64 + 2 * i, zo = ze + 1;
  float qe = zne * ((ag[ze] + 1.f) * rs) + ab[ze];
  float qo = zno * ((ag[zo] + 1.f) * rs) + ab[zo];
  float ke = zne * ((ag[kZ + ze] + 1.f) * rs) + ab[kZ + ze];
  float ko = zno * ((ag[kZ + zo] + 1.f) * rs) + ab[kZ + zo];
  float cs = freqs[((size_t)s * 32 + i) * 2 + 0];
  float sn = freqs[((size_t)s * 32 + i) * 2 + 1];
  size_t o = (((size_t)b * kH + h) * kS + s) * 64 + 2 * i;
  q[o]     = (bf16_t)(qe * cs - qo * sn);
  q[o + 1] = (bf16_t)(qe * sn + qo * cs);
  k[o]     = (bf16_t)(ke * cs - ko * sn);
  k[o + 1] = (bf16_t)(ke * sn + ko * cs);
}

// ---------------- bf16 MFMA GEMM: C[M,N] = A[M,K] @ Bt[N,K]^T --------------
// 128x128 tile, BK=32, 4 waves each 64x64 (4x4 of 16x16x32). m97 structure.
// epi: 0 = +bias -> f32 ; 1 = silu(+bias) -> bf16 transposed vT[b][hd][s]
//      2 = silu(+bias) -> bf16 row-major ; 3 = + add1 + add2 -> f32
__global__ __launch_bounds__(256) void gemm_bt(const bf16_t* __restrict__ A,
    const bf16_t* __restrict__ Bt, int M, int N, int K,
    const float* __restrict__ bias, const float* __restrict__ add1,
    const float* __restrict__ add2, float* __restrict__ outF,
    bf16_t* __restrict__ outB, int epi) {
  __shared__ __align__(16) bf16_t sA[128 * 32];
  __shared__ __align__(16) bf16_t sB[128 * 32];
  const int t = threadIdx.x;
  const int wave = t >> 6, lane = t & 63;
  const int quad = lane >> 4, l16 = lane & 15;
  const int m0 = blockIdx.x * 128, n0 = blockIdx.y * 128;
  const int wm = (wave >> 1) * 64, wn = (wave & 1) * 64;

  floatx4 acc[4][4];
#pragma unroll
  for (int i = 0; i < 4; ++i)
#pragma unroll
    for (int j = 0; j < 4; ++j) acc[i][j] = (floatx4){0.f, 0.f, 0.f, 0.f};

  const int seg0 = wave * 64 + lane;        // segs 0..255
  const int seg1 = 256 + wave * 64 + lane;  // segs 256..511
  const int r0 = seg0 >> 2, c0 = (seg0 & 3) * 8;
  const int r1 = seg1 >> 2, c1 = (seg1 & 3) * 8;

  for (int kt = 0; kt < K; kt += 32) {
    __syncthreads();
    async16(sA + (size_t)(wave * 64) * 8,        A + (size_t)(m0 + r0) * K + kt + c0);
    async16(sA + (size_t)(256 + wave * 64) * 8,  A + (size_t)(m0 + r1) * K + kt + c1);
    async16(sB + (size_t)(wave * 64) * 8,        Bt + (size_t)(n0 + r0) * K + kt + c0);
    async16(sB + (size_t)(256 + wave * 64) * 8,  Bt + (size_t)(n0 + r1) * K + kt + c1);
    __syncthreads();  // compiler drains vmcnt before s_barrier

    bf16x8 af[4], bfr[4];
#pragma unroll
    for (int i = 0; i < 4; ++i)
      af[i] = *(const bf16x8*)(sA + (wm + i * 16 + l16) * 32 + quad * 8);
#pragma unroll
    for (int j = 0; j < 4; ++j)
      bfr[j] = *(const bf16x8*)(sB + (wn + j * 16 + l16) * 32 + quad * 8);
#pragma unroll
    for (int i = 0; i < 4; ++i)
#pragma unroll
      for (int j = 0; j < 4; ++j)
        acc[i][j] = __builtin_amdgcn_mfma_f32_16x16x32_bf16(af[i], bfr[j], acc[i][j], 0, 0, 0);
  }

  // epilogue: C/D layout col=l16, row=quad*4+reg
#pragma unroll
  for (int i = 0; i < 4; ++i) {
#pragma unroll
    for (int j = 0; j < 4; ++j) {
#pragma unroll
      for (int r = 0; r < 4; ++r) {
        int row = m0 + wm + i * 16 + quad * 4 + r;
        int col = n0 + wn + j * 16 + l16;
        size_t idx = (size_t)row * N + col;
        float v = acc[i][j][r];
        if (epi == 0) {
          outF[idx] = v + bias[col];
        } else if (epi == 1) {
          v += bias[col];
          v = v / (1.f + __expf(-v));
          // vT[b][hd][s] : hd = col (0..4095), b = row>>11, s = row&2047
          size_t vidx = ((size_t)(row >> 11) * kHD + col) * (size_t)kS + (row & 2047);
          outB[vidx] = (bf16_t)v;
        } else if (epi == 2) {
          v += bias[col];
          v = v / (1.f + __expf(-v));
          outB[idx] = (bf16_t)v;
        } else {
          outF[idx] = v + add1[idx] + add2[idx];
        }
      }
    }
  }
}

// ---------------- flash attention (causal) + r-gating ----------------------
// grid: (S/64, B*H). block 256 = 4 waves. Wave w: scores for q-rows w*16..+16,
// PV for vh chunk w*128..+128 over all 64 q-rows. P via LDS (bf16).
// q,k: [B][H][S][64] bf16 ; vT: [B][HD][S] bf16 (per (b,h): rows h*512..)
// r, attnG: [B][S][HD] bf16.
__global__ __launch_bounds__(256) void attn_kernel(const bf16_t* __restrict__ qg,
    const bf16_t* __restrict__ kg, const bf16_t* __restrict__ vT,
    const bf16_t* __restrict__ rg, bf16_t* __restrict__ attnG) {
  const int qt = blockIdx.x, bh = blockIdx.y;
  const int b = bh >> 3, h = bh & 7;
  const int t = threadIdx.x;
  const int w = t >> 6, lane = t & 63;
  const int quad = lane >> 4, l16 = lane & 15;
  const int q0 = qt * 64;

  __shared__ __align__(16) bf16_t sP[64 * 64];
  __shared__ float sM[64], sL[64], sAl[64];
  if (t < 64) { sM[t] = -1e30f; sL[t] = 0.f; }

  const bf16_t* qbase = qg + ((size_t)bh * kS + q0) * 64;
  bf16x8 qfrag[2];
#pragma unroll
  for (int ks = 0; ks < 2; ++ks)
    qfrag[ks] = *(const bf16x8*)(qbase + (size_t)(w * 16 + l16) * 64 + ks * 32 + quad * 8);

  floatx4 oacc[4][8];
#pragma unroll
  for (int i = 0; i < 4; ++i)
#pragma unroll
    for (int j = 0; j < 8; ++j) oacc[i][j] = (floatx4){0.f, 0.f, 0.f, 0.f};

  const bf16_t* kbase = kg + (size_t)bh * kS * 64;
  const bf16_t* vbase = vT + (size_t)bh * 512 * kS;  // (b*8+h)*512 rows of vT[b][hd][s]

  __syncthreads();

  for (int kt = 0; kt <= qt; ++kt) {
    const int k0 = kt * 64;
    floatx4 sacc[4];
#pragma unroll
    for (int nt = 0; nt < 4; ++nt) sacc[nt] = (floatx4){0.f, 0.f, 0.f, 0.f};
#pragma unroll
    for (int ks = 0; ks < 2; ++ks)
#pragma unroll
      for (int nt = 0; nt < 4; ++nt) {
        bf16x8 kf = *(const bf16x8*)(kbase + (size_t)(k0 + nt * 16 + l16) * 64 + ks * 32 + quad * 8);
        sacc[nt] = __builtin_amdgcn_mfma_f32_16x16x32_bf16(qfrag[ks], kf, sacc[nt], 0, 0, 0);
      }
    if (kt == qt) {  // causal mask on diagonal tile
#pragma unroll
      for (int nt = 0; nt < 4; ++nt)
#pragma unroll
        for (int r = 0; r < 4; ++r) {
          int sk = k0 + nt * 16 + l16;
          int qq = q0 + w * 16 + quad * 4 + r;
          if (sk > qq) sacc[nt][r] = -1e30f;
        }
    }
    float mloc[4], mnew[4], al[4], lloc[4];
#pragma unroll
    for (int r = 0; r < 4; ++r)
      mloc[r] = fmaxf(fmaxf(sacc[0][r], sacc[1][r]), fmaxf(sacc[2][r], sacc[3][r]));
#pragma unroll
    for (int off = 1; off < 16; off <<= 1)
#pragma unroll
      for (int r = 0; r < 4; ++r) mloc[r] = fmaxf(mloc[r], __shfl_xor(mloc[r], off));
#pragma unroll
    for (int r = 0; r < 4; ++r) {
      int row = w * 16 + quad * 4 + r;
      float mo = sM[row];
      mnew[r] = fmaxf(mo, mloc[r]);
      al[r] = __expf(mo - mnew[r]);
    }
#pragma unroll
    for (int r = 0; r < 4; ++r) {
      float s = 0.f;
#pragma unroll
      for (int nt = 0; nt < 4; ++nt) {
        float e = __expf(sacc[nt][r] - mnew[r]);
        sacc[nt][r] = e;
        s += e;
      }
      lloc[r] = s;
    }
#pragma unroll
    for (int off = 1; off < 16; off <<= 1)
#pragma unroll
      for (int r = 0; r < 4; ++r) lloc[r] += __shfl_xor(lloc[r], off);
    if (l16 == 0) {
#pragma unroll
      for (int r = 0; r < 4; ++r) {
        int row = w * 16 + quad * 4 + r;
        sM[row] = mnew[r];
        sL[row] = al[r] * sL[row] + lloc[r];
        sAl[row] = al[r];
      }
    }
#pragma unroll
    for (int nt = 0; nt < 4; ++nt)
#pragma unroll
      for (int r = 0; r < 4; ++r)
        sP[(w * 16 + quad * 4 + r) * 64 + nt * 16 + l16] = (bf16_t)sacc[nt][r];
    __syncthreads();

    // rescale O then accumulate P @ V
#pragma unroll
    for (int mi = 0; mi < 4; ++mi)
#pragma unroll
      for (int r = 0; r < 4; ++r) {
        float a = sAl[mi * 16 + quad * 4 + r];
#pragma unroll
        for (int nj = 0; nj < 8; ++nj) oacc[mi][nj][r] *= a;
      }
#pragma unroll
    for (int ks = 0; ks < 2; ++ks) {
      bf16x8 pa[4];
#pragma unroll
      for (int mi = 0; mi < 4; ++mi)
        pa[mi] = *(const bf16x8*)(sP + (mi * 16 + l16) * 64 + ks * 32 + quad * 8);
#pragma unroll
      for (int nj = 0; nj < 8; ++nj) {
        bf16x8 vf = *(const bf16x8*)(vbase + (size_t)(w * 128 + nj * 16 + l16) * kS + k0 + ks * 32 + quad * 8);
#pragma unroll
        for (int mi = 0; mi < 4; ++mi)
          oacc[mi][nj] = __builtin_amdgcn_mfma_f32_16x16x32_bf16(pa[mi], vf, oacc[mi][nj], 0, 0, 0);
      }
    }
    __syncthreads();
  }

  // epilogue: O/l * r -> attnG bf16
#pragma unroll
  for (int mi = 0; mi < 4; ++mi)
#pragma unroll
    for (int r = 0; r < 4; ++r) {
      int srow = q0 + mi * 16 + quad * 4 + r;
      float linv = 1.0f / sL[mi * 16 + quad * 4 + r];
#pragma unroll
      for (int nj = 0; nj < 8; ++nj) {
        int hd = h * 512 + w * 128 + nj * 16 + l16;
        size_t idx = ((size_t)b * kS + srow) * kHD + hd;
        float rv = (float)rg[idx];
        attnG[idx] = (bf16_t)(oacc[mi][nj][r] * linv * rv);
      }
    }
}

// ---------------------------------------------------------------------------
extern "C" void kernel_launch(void* const* d_in, const int* in_sizes, int n_in,
                              void* d_out, int out_size, void* d_ws, size_t ws_size,
                              hipStream_t stream) {
  const float* x      = (const float*)d_in[0];
  const float* tnw    = (const float*)d_in[1];
  const float* tnb    = (const float*)d_in[2];
  const float* ealpha = (const float*)d_in[3];
  const float* edelta = (const float*)d_in[4];
  const float* etheta = (const float*)d_in[5];
  const float* egamma = (const float*)d_in[6];
  const float* eomega = (const float*)d_in[7];
  const float* rmsw   = (const float*)d_in[8];
  const float* wz_w   = (const float*)d_in[9];
  const float* wz_b   = (const float*)d_in[10];
  const float* wv_w   = (const float*)d_in[11];
  const float* wv_b   = (const float*)d_in[12];
  const float* wr_w   = (const float*)d_in[13];
  const float* wr_b   = (const float*)d_in[14];
  const float* wh1_w  = (const float*)d_in[15];
  const float* wh1_b  = (const float*)d_in[16];
  const float* wh2_w  = (const float*)d_in[17];
  const float* ag     = (const float*)d_in[18];
  const float* ab     = (const float*)d_in[19];
  const float* freqs  = (const float*)d_in[20];
  float* out = (float*)d_out;

  char* ws = (char*)d_ws;
  size_t off = 0;
  auto alloc = [&](size_t bytes) -> void* {
    void* p = ws + off;
    off += (bytes + 255) & ~(size_t)255;
    return p;
  };
  // buf1: tsn fp32, later reused as vT bf16 (tsn fp32 dead after cema)
  float*  tsn  = (float*)alloc(8388608ull * 4);
  bf16_t* tsnb = (bf16_t*)alloc(8388608ull * 2);
  float*  g1   = (float*)alloc(131072ull * 4);
  float*  g2   = (float*)alloc(131072ull * 4);
  // buf2: cema fp32, later reused as h1 fp32 (cema dead after rms)
  float*  cema = (float*)alloc(8388608ull * 4);
  bf16_t* mx   = (bf16_t*)alloc(8388608ull * 2);
  bf16_t* wzT  = (bf16_t*)alloc(1048576ull * 2);
  bf16_t* wvT  = (bf16_t*)alloc(8388608ull * 2);
  bf16_t* wrT  = (bf16_t*)alloc(8388608ull * 2);
  bf16_t* wh1T = (bf16_t*)alloc(4194304ull * 2);
  bf16_t* wh2T = (bf16_t*)alloc(8388608ull * 2);
  float*  zbuf = (float*)alloc(2097152ull * 4);
  bf16_t* qb   = (bf16_t*)alloc(2097152ull * 2);
  bf16_t* kb   = (bf16_t*)alloc(2097152ull * 2);
  bf16_t* rb   = (bf16_t*)alloc(16777216ull * 2);
  bf16_t* aG   = (bf16_t*)alloc(16777216ull * 2);
  bf16_t* vTb  = (bf16_t*)tsn;   // alias buf1 (16.8M bf16 fits in 33.5MB)
  float*  h1   = cema;           // alias buf2
  // cema scratch: aliases rb/aG — lifetimes disjoint (cema ends before r/attn)
  float2* hend  = (float2*)rb;   // B*C*D*N complex = 16.8 MB (rb is 33.5 MB)
  float2* hinit = (float2*)aG;   // 16.8 MB (aG is 33.5 MB)

  // weights -> bf16, transposed to (N,K)
  wtrans_kernel<<<dim3(kZ / 32, kD / 32), 256, 0, stream>>>(wz_w, wzT, kD, kZ);
  wtrans_kernel<<<dim3(kHD / 32, kD / 32), 256, 0, stream>>>(wv_w, wvT, kD, kHD);
  wtrans_kernel<<<dim3(kHD / 32, kD / 32), 256, 0, stream>>>(wr_w, wrT, kD, kHD);
  wtrans_kernel<<<dim3(kD / 32, kD / 32), 256, 0, stream>>>(wh1_w, wh1T, kD, kD);
  wtrans_kernel<<<dim3(kD / 32, kHD / 32), 256, 0, stream>>>(wh2_w, wh2T, kHD, kD);

  // timestep norm
  tsn_sums<<<kB * kS, 256, 0, stream>>>(x, g1, g2);
  tsn_scan<<<kB * kG, 64, 0, stream>>>(g1, g2);
  tsn_norm<<<kB * kS, 256, 0, stream>>>(x, g1, g2, tnw, tnb, tsn, tsnb);

  // complex EMA + residual omega (chunked parallel scan)
  cema_pass1<<<dim3(kB * kC, kD / 256), 256, 0, stream>>>(tsn, ealpha, edelta,
                                                          etheta, hend);
  cema_pass2<<<kB * kD * 8 / 256, 256, 0, stream>>>(hend, ealpha, edelta,
                                                    etheta, hinit);
  cema_pass3<<<dim3(kB * kC, kD / 256), 256, 0, stream>>>(tsn, ealpha, edelta,
      etheta, egamma, eomega, hinit, cema);
  // mx = rmsnorm(cema) -> bf16
  rms_kernel<<<kB * kS, 256, 0, stream>>>(cema, rmsw, mx);

  const int M = kB * kS;  // 4096
  // z = mx @ wz + b
  gemm_bt<<<dim3(M / 128, kZ / 128), 256, 0, stream>>>(mx, wzT, M, kZ, kD,
      wz_b, nullptr, nullptr, zbuf, nullptr, 0);
  // z -> q,k (per-head rms, gamma/beta, rotary)
  zpost_kernel<<<kB * kS, 256, 0, stream>>>(zbuf, ag, ab, freqs, qb, kb);
  // v = silu(tsn @ wv + b) -> vT[b][hd][s]   (NOTE: after cema; buf1 reuse OK)
  gemm_bt<<<dim3(M / 128, kHD / 128), 256, 0, stream>>>(tsnb, wvT, M, kHD, kD,
      wv_b, nullptr, nullptr, nullptr, vTb, 1);
  // r = silu(mx @ wr + b) -> bf16 row-major
  gemm_bt<<<dim3(M / 128, kHD / 128), 256, 0, stream>>>(mx, wrT, M, kHD, kD,
      wr_b, nullptr, nullptr, nullptr, rb, 2);
  // attention + gating
  attn_kernel<<<dim3(kS / 64, kB * kH), 256, 0, stream>>>(qb, kb, vTb, rb, aG);
  // h1 = mx @ wh1 + b
  gemm_bt<<<dim3(M / 128, kD / 128), 256, 0, stream>>>(mx, wh1T, M, kD, kD,
      wh1_b, nullptr, nullptr, h1, nullptr, 0);
  // out = attnG @ wh2 + h1 + x
  gemm_bt<<<dim3(M / 128, kD / 128), 256, 0, stream>>>(aG, wh2T, M, kD, kHD,
      nullptr, h1, x, out, nullptr, 3);
  (void)in_sizes; (void)n_in; (void)out_size; (void)ws_size;
}